// Round 1
// baseline (296.325 us; speedup 1.0000x reference)
//
#include <hip/hip_runtime.h>
#include <hip/hip_bf16.h>

#define BATCH 4
#define SEQ   4096
#define EMB   1024
#define HD    64
#define N3    192

typedef __attribute__((ext_vector_type(8))) short  short8;
typedef __attribute__((ext_vector_type(4))) float  floatx4;

static __device__ __forceinline__ unsigned short f2bf(float f) {
    unsigned int u = __float_as_uint(f);
    u += 0x7fffu + ((u >> 16) & 1u);          // round-to-nearest-even
    return (unsigned short)(u >> 16);
}

#define MFMA16(A, B, C) __builtin_amdgcn_mfma_f32_16x16x32_bf16(A, B, C, 0, 0, 0)

// ---------------- Stage 1: QKV projection (x @ QKV -> q, k, v^T as bf16) --------
// M=16384 rows, K=1024, N=192. Block: 256 thr (4 waves), 64 rows/block.
__global__ __launch_bounds__(256) void qkv_proj(
    const float* __restrict__ x, const float* __restrict__ w,
    unsigned short* __restrict__ q, unsigned short* __restrict__ k,
    unsigned short* __restrict__ vt)
{
    const int tid = threadIdx.x;
    const int wv  = tid >> 6;
    const int l   = tid & 63;
    const int ln  = l & 15;
    const int g   = l >> 4;
    const int row0 = blockIdx.x * 64;

    __shared__ __align__(16) char Xs[64 * 128];    // [row][k] bf16, swizzled
    __shared__ __align__(16) char Ws[192 * 128];   // [n][k] bf16, swizzled

    floatx4 acc[12];
#pragma unroll
    for (int c = 0; c < 12; ++c) acc[c] = (floatx4){0.f, 0.f, 0.f, 0.f};

    for (int kc = 0; kc < 16; ++kc) {
        __syncthreads();
        // stage X tile: 64 rows x 64 k, fp32->bf16, 4 float4 per thread
#pragma unroll
        for (int i = 0; i < 4; ++i) {
            int idx = tid + i * 256;
            int row = idx >> 4, colq = idx & 15;
            float4 xv = *(const float4*)(x + (size_t)(row0 + row) * EMB + kc * 64 + colq * 4);
            unsigned long long pk =  (unsigned long long)f2bf(xv.x)
                | ((unsigned long long)f2bf(xv.y) << 16)
                | ((unsigned long long)f2bf(xv.z) << 32)
                | ((unsigned long long)f2bf(xv.w) << 48);
            *(unsigned long long*)(Xs + (((row * 128) + colq * 8) ^ ((row & 7) << 4))) = pk;
        }
        // stage W tile transposed: Ws[n][k], 12 float4 per thread
#pragma unroll
        for (int i = 0; i < 12; ++i) {
            int idx = tid + i * 256;
            int kk  = idx / 48;
            int n4  = (idx - kk * 48) * 4;
            float4 wv4 = *(const float4*)(w + (size_t)(kc * 64 + kk) * N3 + n4);
            *(unsigned short*)(Ws + ((((n4 + 0) * 128) + kk * 2) ^ (((n4 + 0) & 7) << 4))) = f2bf(wv4.x);
            *(unsigned short*)(Ws + ((((n4 + 1) * 128) + kk * 2) ^ (((n4 + 1) & 7) << 4))) = f2bf(wv4.y);
            *(unsigned short*)(Ws + ((((n4 + 2) * 128) + kk * 2) ^ (((n4 + 2) & 7) << 4))) = f2bf(wv4.z);
            *(unsigned short*)(Ws + ((((n4 + 3) * 128) + kk * 2) ^ (((n4 + 3) & 7) << 4))) = f2bf(wv4.w);
        }
        __syncthreads();
#pragma unroll
        for (int ks = 0; ks < 2; ++ks) {
            int arow = wv * 16 + ln;
            short8 af = *(const short8*)(Xs + (((arow * 128) + ks * 64 + g * 16) ^ ((arow & 7) << 4)));
#pragma unroll
            for (int c = 0; c < 12; ++c) {
                int brow = c * 16 + ln;
                short8 bf = *(const short8*)(Ws + (((brow * 128) + ks * 64 + g * 16) ^ ((brow & 7) << 4)));
                acc[c] = MFMA16(af, bf, acc[c]);
            }
        }
    }
    // epilogue: C/D layout col=lane&15, row=(lane>>4)*4+reg
#pragma unroll
    for (int c = 0; c < 12; ++c) {
        int n = c * 16 + ln;
#pragma unroll
        for (int j = 0; j < 4; ++j) {
            int grow = row0 + wv * 16 + g * 4 + j;
            int b = grow >> 12;
            int s = grow & 4095;
            unsigned short val = f2bf(acc[c][j]);
            if (n < 64)
                q[(size_t)(b * SEQ + s) * HD + n] = val;
            else if (n < 128)
                k[(size_t)(b * SEQ + s) * HD + (n - 64)] = val;
            else
                vt[((size_t)b * HD + (n - 128)) * SEQ + s] = val;
        }
    }
}

// ---------------- Stage 2: flash attention ----------------
// Block: 256 thr (4 waves), 64 q-rows/block (16 per wave). Key tiles of 64.
__global__ __launch_bounds__(256) void attn(
    const unsigned short* __restrict__ qg, const unsigned short* __restrict__ kg,
    const unsigned short* __restrict__ vtg, float* __restrict__ outg)
{
    const int tid = threadIdx.x;
    const int w   = tid >> 6;
    const int l   = tid & 63;
    const int ln  = l & 15;
    const int g   = l >> 4;
    const int bid = blockIdx.x;
    const int b   = bid >> 6;
    const int qt  = bid & 63;
    const int qr0 = qt * 64 + w * 16;

    __shared__ __align__(16) char Ks[64 * 128];      // [key][d] bf16 swizzled
    __shared__ __align__(16) char Vs[64 * 128];      // [d][key] bf16 swizzled
    __shared__ __align__(16) char Ps[4][16 * 128];   // per-wave P [qrow][key]

    // Q fragments held in registers for the whole kernel
    const unsigned short* qrow = qg + (size_t)(b * SEQ + qr0 + ln) * HD;
    short8 qf0 = *(const short8*)(qrow + g * 8);
    short8 qf1 = *(const short8*)(qrow + 32 + g * 8);

    floatx4 o[4];
    float m_run[4], l_run[4];
#pragma unroll
    for (int c = 0; c < 4; ++c) o[c] = (floatx4){0.f, 0.f, 0.f, 0.f};
#pragma unroll
    for (int j = 0; j < 4; ++j) { m_run[j] = -1e30f; l_run[j] = 0.f; }

    const unsigned short* kbase = kg  + (size_t)b * SEQ * HD;
    const unsigned short* vbase = vtg + (size_t)b * HD * SEQ;
    char* myP = Ps[w];

    const float sscale = 0.125f * 1.4426950408889634f;  // scale * log2(e)

    for (int kt = 0; kt < SEQ / 64; ++kt) {
        __syncthreads();
        // stage K tile [64 keys][64 d] and V^T tile [64 d][64 keys]
#pragma unroll
        for (int i = 0; i < 2; ++i) {
            int u = tid + i * 256;
            int row = u >> 3, un = u & 7;
            uint4 kv = *(const uint4*)(kbase + (size_t)(kt * 64 + row) * HD + un * 8);
            *(uint4*)(Ks + (((row * 128) + un * 16) ^ ((row & 7) << 4))) = kv;
            uint4 vv = *(const uint4*)(vbase + (size_t)row * SEQ + kt * 64 + un * 8);
            *(uint4*)(Vs + (((row * 128) + un * 16) ^ ((row & 7) << 4))) = vv;
        }
        __syncthreads();

        // S = Q K^T for 16 q-rows x 64 keys
        floatx4 sa[4];
#pragma unroll
        for (int c = 0; c < 4; ++c) sa[c] = (floatx4){0.f, 0.f, 0.f, 0.f};
#pragma unroll
        for (int c = 0; c < 4; ++c) {
            int kr = c * 16 + ln;
            short8 kf0 = *(const short8*)(Ks + (((kr * 128) + g * 16) ^ ((kr & 7) << 4)));
            short8 kf1 = *(const short8*)(Ks + (((kr * 128) + 64 + g * 16) ^ ((kr & 7) << 4)));
            sa[c] = MFMA16(qf0, kf0, sa[c]);
            sa[c] = MFMA16(qf1, kf1, sa[c]);
        }
#pragma unroll
        for (int c = 0; c < 4; ++c) sa[c] *= sscale;

        // online softmax (exp2 domain); row r = g*4+j lives in the 16 lanes of group g
        float m_new[4], fac[4], ps[4];
#pragma unroll
        for (int j = 0; j < 4; ++j) {
            float tm = fmaxf(fmaxf(sa[0][j], sa[1][j]), fmaxf(sa[2][j], sa[3][j]));
#pragma unroll
            for (int off = 1; off < 16; off <<= 1)
                tm = fmaxf(tm, __shfl_xor(tm, off));
            m_new[j] = fmaxf(m_run[j], tm);
            fac[j]   = exp2f(m_run[j] - m_new[j]);
            m_run[j] = m_new[j];
            ps[j] = 0.f;
        }
#pragma unroll
        for (int c = 0; c < 4; ++c) {
#pragma unroll
            for (int j = 0; j < 4; ++j) {
                float p = exp2f(sa[c][j] - m_new[j]);
                ps[j] += p;
                int pr = g * 4 + j;
                int pc = c * 16 + ln;
                *(unsigned short*)(myP + (((pr * 128) + pc * 2) ^ ((pr & 7) << 4))) = f2bf(p);
            }
        }
#pragma unroll
        for (int j = 0; j < 4; ++j) {
#pragma unroll
            for (int off = 1; off < 16; off <<= 1)
                ps[j] += __shfl_xor(ps[j], off);
            l_run[j] = l_run[j] * fac[j] + ps[j];
        }
#pragma unroll
        for (int c = 0; c < 4; ++c) {
            floatx4 t = o[c];
            t[0] *= fac[0]; t[1] *= fac[1]; t[2] *= fac[2]; t[3] *= fac[3];
            o[c] = t;
        }
        // P fragments (wave-local LDS transpose), then O += P V
        short8 pa0 = *(const short8*)(myP + (((ln * 128) + g * 16) ^ ((ln & 7) << 4)));
        short8 pa1 = *(const short8*)(myP + (((ln * 128) + 64 + g * 16) ^ ((ln & 7) << 4)));
#pragma unroll
        for (int c = 0; c < 4; ++c) {
            int vr = c * 16 + ln;
            short8 vf0 = *(const short8*)(Vs + (((vr * 128) + g * 16) ^ ((vr & 7) << 4)));
            short8 vf1 = *(const short8*)(Vs + (((vr * 128) + 64 + g * 16) ^ ((vr & 7) << 4)));
            o[c] = MFMA16(pa0, vf0, o[c]);
            o[c] = MFMA16(pa1, vf1, o[c]);
        }
    }

    float inv[4];
#pragma unroll
    for (int j = 0; j < 4; ++j) inv[j] = 1.0f / l_run[j];
#pragma unroll
    for (int c = 0; c < 4; ++c) {
#pragma unroll
        for (int j = 0; j < 4; ++j) {
            outg[(size_t)(b * SEQ + qr0 + g * 4 + j) * HD + c * 16 + ln] = o[c][j] * inv[j];
        }
    }
}

extern "C" void kernel_launch(void* const* d_in, const int* in_sizes, int n_in,
                              void* d_out, int out_size, void* d_ws, size_t ws_size,
                              hipStream_t stream) {
    (void)in_sizes; (void)n_in; (void)out_size; (void)ws_size;
    const float* x = (const float*)d_in[0];
    const float* w = (const float*)d_in[1];
    float* out = (float*)d_out;

    unsigned short* q  = (unsigned short*)d_ws;
    unsigned short* k  = q + (size_t)BATCH * SEQ * HD;
    unsigned short* vt = k + (size_t)BATCH * SEQ * HD;

    qkv_proj<<<dim3(256), dim3(256), 0, stream>>>(x, w, q, k, vt);
    attn<<<dim3(256), dim3(256), 0, stream>>>(q, k, vt, out);
}

// Round 2
// 199.952 us; speedup vs baseline: 1.4820x; 1.4820x over previous
//
#include <hip/hip_runtime.h>
#include <hip/hip_bf16.h>

#define BATCH 4
#define SEQ   4096
#define EMB   1024
#define HD    64
#define N3    192
#define NSPLIT 4

typedef __attribute__((ext_vector_type(8))) short  short8;
typedef __attribute__((ext_vector_type(4))) float  floatx4;
typedef unsigned long long ull;

static __device__ __forceinline__ unsigned short f2bf(float f) {
    unsigned int u = __float_as_uint(f);
    u += 0x7fffu + ((u >> 16) & 1u);          // round-to-nearest-even
    return (unsigned short)(u >> 16);
}

#define MFMA16(A, B, C) __builtin_amdgcn_mfma_f32_16x16x32_bf16(A, B, C, 0, 0, 0)

// ---------------- Stage 0: W fp32 [1024][192] -> Wt bf16 [192][1024] ----------
__global__ __launch_bounds__(256) void wt_prep(const float* __restrict__ w,
                                               unsigned short* __restrict__ wt)
{
    int idx = blockIdx.x * 256 + threadIdx.x;       // 196608 total
    int k = idx / N3;
    int n = idx - k * N3;
    wt[(size_t)n * EMB + k] = f2bf(w[idx]);
}

// ---------------- Stage 1: QKV projection -------------------------------------
// 1024 blocks x 256 thr. Block = 16 rows, full K staged once; waves split N 4x48.
__global__ __launch_bounds__(256, 4) void qkv_proj(
    const float* __restrict__ x, const unsigned short* __restrict__ wt,
    unsigned short* __restrict__ q, unsigned short* __restrict__ k,
    unsigned short* __restrict__ vt)
{
    const int tid = threadIdx.x;
    const int w   = tid >> 6;
    const int l   = tid & 63;
    const int ln  = l & 15;
    const int g   = l >> 4;
    const int row0 = blockIdx.x * 16;

    __shared__ __align__(16) char Xs[16 * 2048];    // [row][k] bf16, swizzled

    // stage X strip: 16 rows x 1024 k, fp32->bf16. row j, lane-consecutive float4.
#pragma unroll
    for (int j = 0; j < 16; ++j) {
        float4 xv = *(const float4*)(x + (size_t)(row0 + j) * EMB + tid * 4);
        ull pk =  (ull)f2bf(xv.x)
            | ((ull)f2bf(xv.y) << 16)
            | ((ull)f2bf(xv.z) << 32)
            | ((ull)f2bf(xv.w) << 48);
        *(ull*)(Xs + (((j * 2048) + tid * 8) ^ ((j & 7) << 4))) = pk;
    }
    __syncthreads();

    floatx4 acc[3];
#pragma unroll
    for (int c = 0; c < 3; ++c) acc[c] = (floatx4){0.f, 0.f, 0.f, 0.f};

    const unsigned short* wbase = wt + (size_t)(w * 48) * EMB;
#pragma unroll 4
    for (int kc = 0; kc < 32; ++kc) {
        short8 af = *(const short8*)(Xs + (((ln * 2048) + kc * 64 + g * 16) ^ ((ln & 7) << 4)));
#pragma unroll
        for (int c = 0; c < 3; ++c) {
            short8 bf = *(const short8*)(wbase + (size_t)(c * 16 + ln) * EMB + kc * 32 + g * 8);
            acc[c] = MFMA16(af, bf, acc[c]);
        }
    }

    // epilogue: C/D layout col=lane&15, row=(lane>>4)*4+reg
#pragma unroll
    for (int c = 0; c < 3; ++c) {
        int n = w * 48 + c * 16 + ln;
#pragma unroll
        for (int j = 0; j < 4; ++j) {
            int grow = row0 + g * 4 + j;
            int b = grow >> 12;
            int s = grow & 4095;
            unsigned short val = f2bf(acc[c][j]);
            if (n < 64)
                q[(size_t)(b * SEQ + s) * HD + n] = val;
            else if (n < 128)
                k[(size_t)(b * SEQ + s) * HD + (n - 64)] = val;
            else
                vt[((size_t)b * HD + (n - 128)) * SEQ + s] = val;
        }
    }
}

// ---------------- Stage 2: flash attention, KV-split x4 -----------------------
// 1024 blocks x 256 thr. Block = (b, qtile64, split); wave = 16 q-rows, 16 key-tiles.
__global__ __launch_bounds__(256, 4) void attn(
    const unsigned short* __restrict__ qg, const unsigned short* __restrict__ kg,
    const unsigned short* __restrict__ vtg,
    float* __restrict__ po, float* __restrict__ pml)
{
    const int tid = threadIdx.x;
    const int w   = tid >> 6;
    const int l   = tid & 63;
    const int ln  = l & 15;
    const int g   = l >> 4;
    const int bid = blockIdx.x;
    const int split = bid & 3;
    const int qt  = (bid >> 2) & 63;
    const int b   = bid >> 8;
    const int qr0 = qt * 64 + w * 16;

    __shared__ __align__(16) char Ks[64 * 128];      // [key][d] bf16 swizzled
    __shared__ __align__(16) char Vs[64 * 128];      // [d][key] bf16 swizzled
    __shared__ __align__(16) char Ps[4][16 * 128];   // per-wave P [qrow][key]

    const unsigned short* qrow = qg + (size_t)(b * SEQ + qr0 + ln) * HD;
    short8 qf0 = *(const short8*)(qrow + g * 8);
    short8 qf1 = *(const short8*)(qrow + 32 + g * 8);

    floatx4 o[4];
    float m_run[4], l_run[4];
#pragma unroll
    for (int c = 0; c < 4; ++c) o[c] = (floatx4){0.f, 0.f, 0.f, 0.f};
#pragma unroll
    for (int j = 0; j < 4; ++j) { m_run[j] = -1e30f; l_run[j] = 0.f; }

    const unsigned short* kbase = kg  + (size_t)b * SEQ * HD;
    const unsigned short* vbase = vtg + (size_t)b * HD * SEQ;
    char* myP = Ps[w];

    const float sscale = 0.125f * 1.4426950408889634f;  // scale * log2(e)

    const int kt0 = split * (SEQ / 64 / NSPLIT);
    for (int kt = kt0; kt < kt0 + SEQ / 64 / NSPLIT; ++kt) {
        __syncthreads();
#pragma unroll
        for (int i = 0; i < 2; ++i) {
            int u = tid + i * 256;
            int row = u >> 3, un = u & 7;
            uint4 kv = *(const uint4*)(kbase + (size_t)(kt * 64 + row) * HD + un * 8);
            *(uint4*)(Ks + (((row * 128) + un * 16) ^ ((row & 7) << 4))) = kv;
            uint4 vv = *(const uint4*)(vbase + (size_t)row * SEQ + kt * 64 + un * 8);
            *(uint4*)(Vs + (((row * 128) + un * 16) ^ ((row & 7) << 4))) = vv;
        }
        __syncthreads();

        // S = Q K^T for 16 q-rows x 64 keys
        floatx4 sa[4];
#pragma unroll
        for (int c = 0; c < 4; ++c) sa[c] = (floatx4){0.f, 0.f, 0.f, 0.f};
        __builtin_amdgcn_s_setprio(1);
#pragma unroll
        for (int c = 0; c < 4; ++c) {
            int kr = c * 16 + ln;
            short8 kf0 = *(const short8*)(Ks + (((kr * 128) + g * 16) ^ ((kr & 7) << 4)));
            short8 kf1 = *(const short8*)(Ks + (((kr * 128) + 64 + g * 16) ^ ((kr & 7) << 4)));
            sa[c] = MFMA16(qf0, kf0, sa[c]);
            sa[c] = MFMA16(qf1, kf1, sa[c]);
        }
        __builtin_amdgcn_s_setprio(0);
#pragma unroll
        for (int c = 0; c < 4; ++c) sa[c] *= sscale;

        // online softmax (exp2 domain); row r = g*4+j lives in 16 lanes of group g
        float m_new[4], fac[4], ps[4];
#pragma unroll
        for (int j = 0; j < 4; ++j) {
            float tm = fmaxf(fmaxf(sa[0][j], sa[1][j]), fmaxf(sa[2][j], sa[3][j]));
#pragma unroll
            for (int off = 1; off < 16; off <<= 1)
                tm = fmaxf(tm, __shfl_xor(tm, off));
            m_new[j] = fmaxf(m_run[j], tm);
            fac[j]   = exp2f(m_run[j] - m_new[j]);
            m_run[j] = m_new[j];
            ps[j] = 0.f;
        }
#pragma unroll
        for (int c = 0; c < 4; ++c) {
#pragma unroll
            for (int j = 0; j < 4; ++j) {
                float p = exp2f(sa[c][j] - m_new[j]);
                ps[j] += p;
                int pr = g * 4 + j;
                int pc = c * 16 + ln;
                *(unsigned short*)(myP + (((pr * 128) + pc * 2) ^ ((pr & 7) << 4))) = f2bf(p);
            }
        }
#pragma unroll
        for (int j = 0; j < 4; ++j) {
#pragma unroll
            for (int off = 1; off < 16; off <<= 1)
                ps[j] += __shfl_xor(ps[j], off);
            l_run[j] = l_run[j] * fac[j] + ps[j];
        }
#pragma unroll
        for (int c = 0; c < 4; ++c) {
            floatx4 t = o[c];
            t[0] *= fac[0]; t[1] *= fac[1]; t[2] *= fac[2]; t[3] *= fac[3];
            o[c] = t;
        }
        short8 pa0 = *(const short8*)(myP + (((ln * 128) + g * 16) ^ ((ln & 7) << 4)));
        short8 pa1 = *(const short8*)(myP + (((ln * 128) + 64 + g * 16) ^ ((ln & 7) << 4)));
        __builtin_amdgcn_s_setprio(1);
#pragma unroll
        for (int c = 0; c < 4; ++c) {
            int vr = c * 16 + ln;
            short8 vf0 = *(const short8*)(Vs + (((vr * 128) + g * 16) ^ ((vr & 7) << 4)));
            short8 vf1 = *(const short8*)(Vs + (((vr * 128) + 64 + g * 16) ^ ((vr & 7) << 4)));
            o[c] = MFMA16(pa0, vf0, o[c]);
            o[c] = MFMA16(pa1, vf1, o[c]);
        }
        __builtin_amdgcn_s_setprio(0);
    }

    // write unnormalized partials + (m, l)
    const size_t prow0 = (size_t)split * (BATCH * SEQ) + (size_t)b * SEQ + qr0;
#pragma unroll
    for (int c = 0; c < 4; ++c) {
#pragma unroll
        for (int j = 0; j < 4; ++j) {
            po[(prow0 + g * 4 + j) * HD + c * 16 + ln] = o[c][j];
        }
    }
    if (ln == 0) {
#pragma unroll
        for (int j = 0; j < 4; ++j) {
            pml[(prow0 + g * 4 + j) * 2 + 0] = m_run[j];
            pml[(prow0 + g * 4 + j) * 2 + 1] = l_run[j];
        }
    }
}

// ---------------- Stage 3: recombine the 4 KV-splits --------------------------
__global__ __launch_bounds__(256) void recombine(
    const float* __restrict__ po, const float* __restrict__ pml,
    float* __restrict__ out)
{
    int idx = blockIdx.x * 256 + threadIdx.x;   // 262144 = 16384 rows x 16 col4
    int row = idx >> 4;
    int c4  = idx & 15;

    float m[NSPLIT], lv[NSPLIT];
#pragma unroll
    for (int i = 0; i < NSPLIT; ++i) {
        m[i]  = pml[((size_t)i * (BATCH * SEQ) + row) * 2 + 0];
        lv[i] = pml[((size_t)i * (BATCH * SEQ) + row) * 2 + 1];
    }
    float M = fmaxf(fmaxf(m[0], m[1]), fmaxf(m[2], m[3]));
    float wt[NSPLIT], denom = 0.f;
#pragma unroll
    for (int i = 0; i < NSPLIT; ++i) { wt[i] = exp2f(m[i] - M); denom += wt[i] * lv[i]; }
    float inv = 1.0f / denom;

    float4 r = {0.f, 0.f, 0.f, 0.f};
#pragma unroll
    for (int i = 0; i < NSPLIT; ++i) {
        float4 ov = *(const float4*)(po + ((size_t)i * (BATCH * SEQ) + row) * HD + c4 * 4);
        r.x += wt[i] * ov.x; r.y += wt[i] * ov.y; r.z += wt[i] * ov.z; r.w += wt[i] * ov.w;
    }
    r.x *= inv; r.y *= inv; r.z *= inv; r.w *= inv;
    *(float4*)(out + (size_t)row * HD + c4 * 4) = r;
}

extern "C" void kernel_launch(void* const* d_in, const int* in_sizes, int n_in,
                              void* d_out, int out_size, void* d_ws, size_t ws_size,
                              hipStream_t stream) {
    (void)in_sizes; (void)n_in; (void)out_size; (void)ws_size;
    const float* x = (const float*)d_in[0];
    const float* w = (const float*)d_in[1];
    float* out = (float*)d_out;

    const size_t QE = (size_t)BATCH * SEQ * HD;       // 1048576
    unsigned short* q   = (unsigned short*)d_ws;
    unsigned short* k   = q + QE;
    unsigned short* vt  = k + QE;
    unsigned short* wtb = vt + QE;
    float* po  = (float*)(wtb + (size_t)N3 * EMB);    // 4 splits x 16384 x 64 fp32
    float* pml = po + (size_t)NSPLIT * BATCH * SEQ * HD;

    wt_prep  <<<dim3(768),  dim3(256), 0, stream>>>(w, wtb);
    qkv_proj <<<dim3(1024), dim3(256), 0, stream>>>(x, wtb, q, k, vt);
    attn     <<<dim3(1024), dim3(256), 0, stream>>>(q, k, vt, po, pml);
    recombine<<<dim3(1024), dim3(256), 0, stream>>>(po, pml, out);
}

// Round 3
// 174.495 us; speedup vs baseline: 1.6982x; 1.1459x over previous
//
#include <hip/hip_runtime.h>
#include <hip/hip_bf16.h>

#define BATCH 4
#define SEQ   4096
#define EMB   1024
#define HD    64
#define N3    192
#define NSPLIT 8

typedef __attribute__((ext_vector_type(8)))  short short8;
typedef __attribute__((ext_vector_type(4)))  float floatx4;
typedef __attribute__((ext_vector_type(16))) float floatx16;
typedef unsigned long long ull;
typedef unsigned short us;

#define SSCALE 0.1803368801111204f   /* 0.125 * log2(e) */

static __device__ __forceinline__ us f2bf(float f) {
    unsigned int u = __float_as_uint(f);
    u += 0x7fffu + ((u >> 16) & 1u);
    return (us)(u >> 16);
}
static __device__ __forceinline__ float bf2f(us h) {
    return __uint_as_float((unsigned int)h << 16);
}
static __device__ __forceinline__ unsigned int cvtpk(float lo, float hi) {
    unsigned int r;
    asm("v_cvt_pk_bf16_f32 %0, %1, %2" : "=v"(r) : "v"(lo), "v"(hi));
    return r;
}
static __device__ __forceinline__ void gll16(const void* g, void* l) {
    __builtin_amdgcn_global_load_lds(
        (const __attribute__((address_space(1))) unsigned int*)(unsigned long long)g,
        (__attribute__((address_space(3))) unsigned int*)(unsigned int)(unsigned long long)l,
        16, 0, 0);
}

#define MFMA16(A, B, C) __builtin_amdgcn_mfma_f32_16x16x32_bf16(A, B, C, 0, 0, 0)
#define MFMA32(A, B, C) __builtin_amdgcn_mfma_f32_32x32x16_bf16(A, B, C, 0, 0, 0)

// ---------------- Stage 0: W fp32 [1024][192] -> Wt bf16 [192][1024] ----------
__global__ __launch_bounds__(256) void wt_prep(const float* __restrict__ w,
                                               us* __restrict__ wt)
{
    int idx = blockIdx.x * 256 + threadIdx.x;
    int k = idx / N3;
    int n = idx - k * N3;
    wt[(size_t)n * EMB + k] = f2bf(w[idx]);
}

// ---------------- Stage 1: QKV projection (q pre-scaled by 0.125*log2e) -------
__global__ __launch_bounds__(256, 4) void qkv_proj(
    const float* __restrict__ x, const us* __restrict__ wt,
    us* __restrict__ q, us* __restrict__ k, us* __restrict__ vt)
{
    const int tid = threadIdx.x;
    const int w   = tid >> 6;
    const int l   = tid & 63;
    const int ln  = l & 15;
    const int g   = l >> 4;
    const int row0 = blockIdx.x * 16;

    __shared__ __align__(16) char Xs[16 * 2048];

#pragma unroll
    for (int j = 0; j < 16; ++j) {
        float4 xv = *(const float4*)(x + (size_t)(row0 + j) * EMB + tid * 4);
        ull pk =  (ull)f2bf(xv.x)
            | ((ull)f2bf(xv.y) << 16)
            | ((ull)f2bf(xv.z) << 32)
            | ((ull)f2bf(xv.w) << 48);
        *(ull*)(Xs + (((j * 2048) + tid * 8) ^ ((j & 7) << 4))) = pk;
    }
    __syncthreads();

    floatx4 acc[3];
#pragma unroll
    for (int c = 0; c < 3; ++c) acc[c] = (floatx4){0.f, 0.f, 0.f, 0.f};

    const us* wbase = wt + (size_t)(w * 48) * EMB;
#pragma unroll 4
    for (int kc = 0; kc < 32; ++kc) {
        short8 af = *(const short8*)(Xs + (((ln * 2048) + kc * 64 + g * 16) ^ ((ln & 7) << 4)));
#pragma unroll
        for (int c = 0; c < 3; ++c) {
            short8 bf = *(const short8*)(wbase + (size_t)(c * 16 + ln) * EMB + kc * 32 + g * 8);
            acc[c] = MFMA16(af, bf, acc[c]);
        }
    }

#pragma unroll
    for (int c = 0; c < 3; ++c) {
        int n = w * 48 + c * 16 + ln;
#pragma unroll
        for (int j = 0; j < 4; ++j) {
            int grow = row0 + g * 4 + j;
            int b = grow >> 12;
            int s = grow & 4095;
            if (n < 64)
                q[(size_t)(b * SEQ + s) * HD + n] = f2bf(acc[c][j] * SSCALE);
            else if (n < 128)
                k[(size_t)(b * SEQ + s) * HD + (n - 64)] = f2bf(acc[c][j]);
            else
                vt[((size_t)b * HD + (n - 128)) * SEQ + s] = f2bf(acc[c][j]);
        }
    }
}

// ---------------- Stage 2: flash attention, 32x32 swapped, KV-split x8 --------
// 1024 blocks x 256 thr. Block = 128 q-rows (4 waves x 32), 8 key-tiles of 64.
__global__ __launch_bounds__(256, 4) void attn(
    const us* __restrict__ qg, const us* __restrict__ kg,
    const us* __restrict__ vtg, us* __restrict__ pob, float* __restrict__ pml)
{
    const int tid = threadIdx.x;
    const int w   = tid >> 6;
    const int l   = tid & 63;
    const int qn  = l & 31;
    const int u   = l >> 5;
    const int bid = blockIdx.x;
    const int split = bid & 7;          // split == XCD -> KV split is L2-resident
    const int qt  = (bid >> 3) & 31;
    const int b   = bid >> 8;
    const int qr0 = qt * 128 + w * 32;

    __shared__ __align__(16) char LDSbuf[32768];   // 2 x (K 8KB + V 8KB); reused as Ts

    const us* kbase = kg  + (size_t)b * SEQ * HD;
    const us* vbase = vtg + (size_t)b * HD * SEQ;

    // Q fragments (B-operand of swapped QK^T): Q[q=qn][d = 16t + 8u + e]
    const us* qrow = qg + ((size_t)(b * SEQ) + qr0 + qn) * HD;
    short8 qf[4];
#pragma unroll
    for (int t = 0; t < 4; ++t) qf[t] = *(const short8*)(qrow + t * 16 + u * 8);

    const int ktbase = split * 8;

    // stage one 64-key tile (K: [key][d], V^T: [d][key]) via global_load_lds,
    // linear LDS dest + inverse-swizzled global source (swizzle: byte ^= (row&7)<<4)
    auto stage = [&](int ktg, char* Kd, char* Vd) {
#pragma unroll
        for (int j = 0; j < 2; ++j) {
            int idx = w * 2 + j;                 // 0..7 across 4 waves
            int row = idx * 8 + (l >> 3);        // 0..63
            int c16 = (l & 7) ^ (row & 7);
            gll16(kbase + (size_t)(ktg * 64 + row) * HD + c16 * 8, Kd + idx * 1024);
            gll16(vbase + (size_t)row * SEQ + ktg * 64 + c16 * 8, Vd + idx * 1024);
        }
    };

    stage(ktbase, LDSbuf, LDSbuf + 8192);

    floatx16 o0 = {}, o1 = {};
    float m_run = -1e30f, l_run = 0.f;

    for (int kt = 0; kt < 8; ++kt) {
        asm volatile("s_waitcnt vmcnt(0)" ::: "memory");
        __syncthreads();
        char* Ks = LDSbuf + (kt & 1) * 16384;
        char* Vs = Ks + 8192;
        if (kt < 7) {
            char* Kn = LDSbuf + ((kt + 1) & 1) * 16384;
            stage(ktbase + kt + 1, Kn, Kn + 8192);
        }

        // S^T = K Q^T : A = K-frag (rows keys), B = Q-frag (cols q)
        floatx16 sa0 = {}, sa1 = {};
        __builtin_amdgcn_s_setprio(1);
#pragma unroll
        for (int t = 0; t < 4; ++t) {
            int r0 = qn, r1 = 32 + qn;
            short8 kf0 = *(const short8*)(Ks + r0 * 128 + ((32 * t + 16 * u) ^ ((r0 & 7) << 4)));
            short8 kf1 = *(const short8*)(Ks + r1 * 128 + ((32 * t + 16 * u) ^ ((r1 & 7) << 4)));
            sa0 = MFMA32(kf0, qf[t], sa0);
            sa1 = MFMA32(kf1, qf[t], sa1);
        }
        __builtin_amdgcn_s_setprio(0);

        // online softmax in exp2 domain; lane owns full row q = qn (with partner l^32)
        float tm = sa0[0];
#pragma unroll
        for (int r = 1; r < 16; ++r) tm = fmaxf(tm, sa0[r]);
#pragma unroll
        for (int r = 0; r < 16; ++r) tm = fmaxf(tm, sa1[r]);
        tm = fmaxf(tm, __shfl_xor(tm, 32));

        if (!__all(tm <= m_run + 8.f)) {       // T13 defer-max, THR=8
            float mn  = fmaxf(m_run, tm);
            float fac = exp2f(m_run - mn);
            m_run = mn;
            l_run *= fac;
#pragma unroll
            for (int r = 0; r < 16; ++r) { o0[r] *= fac; o1[r] *= fac; }
        }
        float ls = 0.f;
#pragma unroll
        for (int r = 0; r < 16; ++r) { float p = exp2f(sa0[r] - m_run); sa0[r] = p; ls += p; }
#pragma unroll
        for (int r = 0; r < 16; ++r) { float p = exp2f(sa1[r] - m_run); sa1[r] = p; ls += p; }
        ls += __shfl_xor(ls, 32);
        l_run += ls;

        // O^T += V^T P^T : per K-step s build P^T B-frag in-register (T12)
        __builtin_amdgcn_s_setprio(1);
#pragma unroll
        for (int s = 0; s < 4; ++s) {
            unsigned int A0, A1, B0, B1;
            if (s == 0) {
                A0 = cvtpk(sa0[0], sa0[1]);  A1 = cvtpk(sa0[2], sa0[3]);
                B0 = cvtpk(sa0[4], sa0[5]);  B1 = cvtpk(sa0[6], sa0[7]);
            } else if (s == 1) {
                A0 = cvtpk(sa0[8], sa0[9]);  A1 = cvtpk(sa0[10], sa0[11]);
                B0 = cvtpk(sa0[12], sa0[13]); B1 = cvtpk(sa0[14], sa0[15]);
            } else if (s == 2) {
                A0 = cvtpk(sa1[0], sa1[1]);  A1 = cvtpk(sa1[2], sa1[3]);
                B0 = cvtpk(sa1[4], sa1[5]);  B1 = cvtpk(sa1[6], sa1[7]);
            } else {
                A0 = cvtpk(sa1[8], sa1[9]);  A1 = cvtpk(sa1[10], sa1[11]);
                B0 = cvtpk(sa1[12], sa1[13]); B1 = cvtpk(sa1[14], sa1[15]);
            }
            asm("v_permlane32_swap_b32 %0, %1" : "+v"(A0), "+v"(B0));
            asm("v_permlane32_swap_b32 %0, %1" : "+v"(A1), "+v"(B1));
            int4 pbv = {(int)A0, (int)A1, (int)B0, (int)B1};
            short8 pb = *(short8*)&pbv;

            int rv0 = qn, rv1 = 32 + qn;
            short8 vf0 = *(const short8*)(Vs + rv0 * 128 + ((32 * s + 16 * u) ^ ((rv0 & 7) << 4)));
            short8 vf1 = *(const short8*)(Vs + rv1 * 128 + ((32 * s + 16 * u) ^ ((rv1 & 7) << 4)));
            o0 = MFMA32(vf0, pb, o0);
            o1 = MFMA32(vf1, pb, o1);
        }
        __builtin_amdgcn_s_setprio(0);
    }

    // epilogue: transpose O^T -> O through wave-local LDS, write bf16 partials
    __syncthreads();
    float* Ts = (float*)(LDSbuf + w * 8192);   // [d 64][q 32]
#pragma unroll
    for (int r = 0; r < 16; ++r) {
        int d = (r & 3) + 8 * (r >> 2) + 4 * u;
        Ts[d * 32 + qn]        = o0[r];
        Ts[(d + 32) * 32 + qn] = o1[r];
    }
    __builtin_amdgcn_s_waitcnt(0);  // lgkm handled by compiler on read below
    const size_t prow0 = (size_t)split * (BATCH * SEQ) + (size_t)b * SEQ + qr0;
#pragma unroll
    for (int c = 0; c < 8; ++c) {
        float v0 = Ts[(u * 32 + c * 4 + 0) * 32 + qn];
        float v1 = Ts[(u * 32 + c * 4 + 1) * 32 + qn];
        float v2 = Ts[(u * 32 + c * 4 + 2) * 32 + qn];
        float v3 = Ts[(u * 32 + c * 4 + 3) * 32 + qn];
        ull pk =  (ull)f2bf(v0) | ((ull)f2bf(v1) << 16)
               | ((ull)f2bf(v2) << 32) | ((ull)f2bf(v3) << 48);
        *(ull*)(pob + (prow0 + qn) * HD + u * 32 + c * 4) = pk;
    }
    if (l < 32) {
        pml[(prow0 + l) * 2 + 0] = m_run;
        pml[(prow0 + l) * 2 + 1] = l_run;
    }
}

// ---------------- Stage 3: recombine the 8 KV-splits --------------------------
__global__ __launch_bounds__(256) void recombine(
    const us* __restrict__ pob, const float* __restrict__ pml,
    float* __restrict__ out)
{
    int idx = blockIdx.x * 256 + threadIdx.x;   // 131072 = 16384 rows x 8 chunks
    int row = idx >> 3;
    int c8  = idx & 7;

    float m[NSPLIT], lv[NSPLIT];
#pragma unroll
    for (int i = 0; i < NSPLIT; ++i) {
        m[i]  = pml[((size_t)i * (BATCH * SEQ) + row) * 2 + 0];
        lv[i] = pml[((size_t)i * (BATCH * SEQ) + row) * 2 + 1];
    }
    float M = m[0];
#pragma unroll
    for (int i = 1; i < NSPLIT; ++i) M = fmaxf(M, m[i]);
    float wt[NSPLIT], denom = 0.f;
#pragma unroll
    for (int i = 0; i < NSPLIT; ++i) { wt[i] = exp2f(m[i] - M); denom += wt[i] * lv[i]; }
    float inv = 1.0f / denom;

    float acc[8];
#pragma unroll
    for (int e = 0; e < 8; ++e) acc[e] = 0.f;
#pragma unroll
    for (int i = 0; i < NSPLIT; ++i) {
        short8 v = *(const short8*)(pob + ((size_t)i * (BATCH * SEQ) + row) * HD + c8 * 8);
#pragma unroll
        for (int e = 0; e < 8; ++e) acc[e] += wt[i] * bf2f((us)v[e]);
    }
    float4 r0 = {acc[0] * inv, acc[1] * inv, acc[2] * inv, acc[3] * inv};
    float4 r1 = {acc[4] * inv, acc[5] * inv, acc[6] * inv, acc[7] * inv};
    *(float4*)(out + (size_t)row * HD + c8 * 8)     = r0;
    *(float4*)(out + (size_t)row * HD + c8 * 8 + 4) = r1;
}

extern "C" void kernel_launch(void* const* d_in, const int* in_sizes, int n_in,
                              void* d_out, int out_size, void* d_ws, size_t ws_size,
                              hipStream_t stream) {
    (void)in_sizes; (void)n_in; (void)out_size; (void)ws_size;
    const float* x = (const float*)d_in[0];
    const float* w = (const float*)d_in[1];
    float* out = (float*)d_out;

    const size_t QE = (size_t)BATCH * SEQ * HD;       // 1048576
    us* q   = (us*)d_ws;
    us* k   = q + QE;
    us* vt  = k + QE;
    us* wtb = vt + QE;
    us* pob = wtb + (size_t)N3 * EMB;                 // 8 x 16384 x 64 bf16
    float* pml = (float*)(pob + (size_t)NSPLIT * BATCH * SEQ * HD);

    wt_prep  <<<dim3(768),  dim3(256), 0, stream>>>(w, wtb);
    qkv_proj <<<dim3(1024), dim3(256), 0, stream>>>(x, wtb, q, k, vt);
    attn     <<<dim3(1024), dim3(256), 0, stream>>>(q, k, vt, pob, pml);
    recombine<<<dim3(512),  dim3(256), 0, stream>>>(pob, pml, out);
}